// Round 1
// baseline (521.551 us; speedup 1.0000x reference)
//
#include <hip/hip_runtime.h>

typedef unsigned short u16;
typedef __attribute__((ext_vector_type(8))) short bf16x8;
typedef __attribute__((ext_vector_type(4))) float f32x4;

#define CDIM 256
#define NDIM 16384
#define NBATCH 8
#define TLEN 64
#define SCHUNK 16
#define NC (NDIM / SCHUNK)

// ws layout (bytes)
#define WS_WK  0u          // Wk bf16 [256][256]  -> 131072
#define WS_WV  131072u     // Wv bf16 [256][256]  -> 131072
#define WS_CTX 262144u     // ctx fp32 [8][256][256] -> 2097152
#define WS_L   2359296u    // l fp32 [8][256] -> 8192
#define WS_END 2367488u

__device__ __forceinline__ u16 f2bf(float f) {
  union { float f; unsigned u; } v; v.f = f;
  return (u16)((v.u + 0x7fffu + ((v.u >> 16) & 1u)) >> 16);
}

__global__ void prep_weights(const float* __restrict__ Wk, const float* __restrict__ Wv,
                             u16* __restrict__ wkb, u16* __restrict__ wvb) {
  int i = blockIdx.x * 256 + threadIdx.x;   // grid 256 -> 65536 threads
  wkb[i] = f2bf(Wk[i]);
  wvb[i] = f2bf(Wv[i]);
}

__global__ __launch_bounds__(256, 2) void attn_main(
    const float* __restrict__ x, const u16* __restrict__ wkb, const u16* __restrict__ wvb,
    float* __restrict__ ctx_acc, float* __restrict__ l_acc) {
  // c-blocked layouts: inner dim = 8 contiguous contraction elements (16B) per fragment read
  __shared__ u16 xs[32][TLEN][8];   // x tile:  [c>>3][n][c&7]   32 KB
  __shared__ u16 ps[8][128][8];     // P tile:  [n>>3][kq][n&7]  16 KB
  __shared__ u16 vs[8][128][8];     // V tile:  [n>>3][v][n&7]   16 KB

  const int bid = blockIdx.x;
  const int kt = (bid >> 1) & 1;          // k-half
  const int vt = bid & 1;                 // v-half
  const int chunk = (bid >> 2) & (SCHUNK - 1);
  const int b = bid >> 6;

  const int tid = threadIdx.x;
  const int wave = tid >> 6;
  const int lane = tid & 63;
  const int l15 = lane & 15;
  const int l4 = lane >> 4;
  const int wr = wave >> 1;               // ctx wave grid 2x2
  const int wc = wave & 1;

  f32x4 cacc[4][4] = {};                  // ctx accumulator: wave tile 64x64
  float lreg[2][4] = {};                  // denominator partials (valid on all lanes of each 16-group)

  const float* xb = x + (size_t)b * CDIM * NDIM + (size_t)chunk * NC;
  const int krow0 = kt * 128 + wave * 32 + l15;   // S-GEMM A rows (rf adds 16)
  const int vrow0 = vt * 128 + wave * 32 + l15;   // V-GEMM A rows

  for (int t = 0; t < NC / TLEN; ++t) {
    const float* xt = xb + t * TLEN;

    // ---- stage x tile -> LDS (fp32 -> bf16, c-blocked transpose) ----
    {
      const int c0 = tid >> 4;            // 0..15
      const int nq = (tid & 15) * 4;      // 0..60
      #pragma unroll
      for (int p = 0; p < 16; ++p) {
        const int c = c0 + p * 16;
        const float4 v4 = *reinterpret_cast<const float4*>(&xt[(size_t)c * NDIM + nq]);
        xs[c >> 3][nq + 0][c & 7] = f2bf(v4.x);
        xs[c >> 3][nq + 1][c & 7] = f2bf(v4.y);
        xs[c >> 3][nq + 2][c & 7] = f2bf(v4.z);
        xs[c >> 3][nq + 3][c & 7] = f2bf(v4.w);
      }
    }
    __syncthreads();

    // ---- S = Wk @ x  (this block's 128 k-rows; wave owns 32 rows x 64 cols) ----
    f32x4 sacc[2][4] = {};
    #pragma unroll
    for (int kk = 0; kk < 8; ++kk) {
      const int c0 = kk * 32 + l4 * 8;
      const bf16x8 a0 = *reinterpret_cast<const bf16x8*>(&wkb[krow0 * 256 + c0]);
      const bf16x8 a1 = *reinterpret_cast<const bf16x8*>(&wkb[(krow0 + 16) * 256 + c0]);
      #pragma unroll
      for (int cf = 0; cf < 4; ++cf) {
        const int n = cf * 16 + l15;
        const bf16x8 bx = *reinterpret_cast<const bf16x8*>(&xs[c0 >> 3][n][0]);
        sacc[0][cf] = __builtin_amdgcn_mfma_f32_16x16x32_bf16(a0, bx, sacc[0][cf], 0, 0, 0);
        sacc[1][cf] = __builtin_amdgcn_mfma_f32_16x16x32_bf16(a1, bx, sacc[1][cf], 0, 0, 0);
      }
    }

    // ---- P = exp(S): write to LDS, accumulate row sums (denominator) ----
    #pragma unroll
    for (int rf = 0; rf < 2; ++rf) {
      float rs[4] = {0.f, 0.f, 0.f, 0.f};
      #pragma unroll
      for (int cf = 0; cf < 4; ++cf) {
        const int n = cf * 16 + l15;
        #pragma unroll
        for (int r = 0; r < 4; ++r) {
          const float pe = __expf(sacc[rf][cf][r]);
          rs[r] += pe;
          ps[n >> 3][wave * 32 + rf * 16 + l4 * 4 + r][n & 7] = f2bf(pe);
        }
      }
      #pragma unroll
      for (int r = 0; r < 4; ++r) {
        float s2 = rs[r];
        s2 += __shfl_xor(s2, 1);
        s2 += __shfl_xor(s2, 2);
        s2 += __shfl_xor(s2, 4);
        s2 += __shfl_xor(s2, 8);
        lreg[rf][r] += s2;
      }
    }

    // ---- V = Wv @ x ----
    f32x4 vacc[2][4] = {};
    #pragma unroll
    for (int kk = 0; kk < 8; ++kk) {
      const int c0 = kk * 32 + l4 * 8;
      const bf16x8 a0 = *reinterpret_cast<const bf16x8*>(&wvb[vrow0 * 256 + c0]);
      const bf16x8 a1 = *reinterpret_cast<const bf16x8*>(&wvb[(vrow0 + 16) * 256 + c0]);
      #pragma unroll
      for (int cf = 0; cf < 4; ++cf) {
        const int n = cf * 16 + l15;
        const bf16x8 bx = *reinterpret_cast<const bf16x8*>(&xs[c0 >> 3][n][0]);
        vacc[0][cf] = __builtin_amdgcn_mfma_f32_16x16x32_bf16(a0, bx, vacc[0][cf], 0, 0, 0);
        vacc[1][cf] = __builtin_amdgcn_mfma_f32_16x16x32_bf16(a1, bx, vacc[1][cf], 0, 0, 0);
      }
    }
    #pragma unroll
    for (int rf = 0; rf < 2; ++rf)
      #pragma unroll
      for (int cf = 0; cf < 4; ++cf) {
        const int n = cf * 16 + l15;
        #pragma unroll
        for (int r = 0; r < 4; ++r)
          vs[n >> 3][wave * 32 + rf * 16 + l4 * 4 + r][n & 7] = f2bf(vacc[rf][cf][r]);
      }
    __syncthreads();

    // ---- ctx += P @ V^T (wave computes its 64x64 quadrant of the 128x128 tile) ----
    #pragma unroll
    for (int kk = 0; kk < 2; ++kk) {
      const int n0 = kk * 32 + l4 * 8;
      bf16x8 bfr[4];
      #pragma unroll
      for (int cf = 0; cf < 4; ++cf)
        bfr[cf] = *reinterpret_cast<const bf16x8*>(&vs[n0 >> 3][wc * 64 + cf * 16 + l15][0]);
      #pragma unroll
      for (int af = 0; af < 4; ++af) {
        const bf16x8 pa = *reinterpret_cast<const bf16x8*>(&ps[n0 >> 3][wr * 64 + af * 16 + l15][0]);
        #pragma unroll
        for (int cf = 0; cf < 4; ++cf)
          cacc[af][cf] = __builtin_amdgcn_mfma_f32_16x16x32_bf16(pa, bfr[cf], cacc[af][cf], 0, 0, 0);
      }
    }
    __syncthreads();
  }

  // ---- epilogue: accumulate partial context + denominators ----
  float* ctxb = ctx_acc + (size_t)b * 256 * 256;
  #pragma unroll
  for (int af = 0; af < 4; ++af) {
    const int kq = kt * 128 + wr * 64 + af * 16 + l4 * 4;
    #pragma unroll
    for (int cf = 0; cf < 4; ++cf) {
      const int vg = vt * 128 + wc * 64 + cf * 16 + l15;
      #pragma unroll
      for (int r = 0; r < 4; ++r)
        atomicAdd(&ctxb[(kq + r) * 256 + vg], cacc[af][cf][r]);
    }
  }
  if (vt == 0 && l15 == 0) {
    #pragma unroll
    for (int rf = 0; rf < 2; ++rf)
      #pragma unroll
      for (int r = 0; r < 4; ++r)
        atomicAdd(&l_acc[b * 256 + kt * 128 + wave * 32 + rf * 16 + l4 * 4 + r], lreg[rf][r]);
  }
}

__global__ void finalize_kernel(const float* __restrict__ ctx_acc, const float* __restrict__ l_acc,
                                const float* __restrict__ bv, float* __restrict__ out) {
  int idx = blockIdx.x * 256 + threadIdx.x;   // grid 2048 -> 524288
  out[idx] = ctx_acc[idx] / l_acc[idx >> 8] + bv[idx & 255];
}

extern "C" void kernel_launch(void* const* d_in, const int* in_sizes, int n_in,
                              void* d_out, int out_size, void* d_ws, size_t ws_size,
                              hipStream_t stream) {
  const float* x  = (const float*)d_in[0];
  const float* Wk = (const float*)d_in[1];
  // d_in[2] = bk: cancels exactly in the softmax (constant over n) -> unused
  const float* Wv = (const float*)d_in[3];
  const float* bv = (const float*)d_in[4];
  float* out = (float*)d_out;
  char* ws = (char*)d_ws;

  u16* wkb = (u16*)(ws + WS_WK);
  u16* wvb = (u16*)(ws + WS_WV);
  float* ctx = (float*)(ws + WS_CTX);
  float* l   = (float*)(ws + WS_L);

  // zero the accumulators (ws is poisoned before every launch)
  hipMemsetAsync(ws + WS_CTX, 0, WS_END - WS_CTX, stream);
  prep_weights<<<256, 256, 0, stream>>>(Wk, Wv, wkb, wvb);
  attn_main<<<NBATCH * SCHUNK * 4, 256, 0, stream>>>(x, wkb, wvb, ctx, l);
  finalize_kernel<<<2048, 256, 0, stream>>>(ctx, l, bv, out);
}